// Round 1
// baseline (986.155 us; speedup 1.0000x reference)
//
#include <hip/hip_runtime.h>
#include <hip/hip_bf16.h>

#define B_ 256
#define T_ 512
#define IN_ 202
#define HID_ 100
#define K_ 19
#define HSTRIDE 9712  // 511*19=9709 padded to 16

__device__ __forceinline__ float rl_f(float v, int l) {
#if __has_builtin(__builtin_amdgcn_readlane)
  return __int_as_float(__builtin_amdgcn_readlane(__float_as_int(v), l));
#else
  return __shfl(v, l, 64);
#endif
}

// ---------------- K1: pre[(b*T+t)*200 + dir*100 + j] = x . w_ih^T + b_ih + b_hh
__global__ __launch_bounds__(256, 1) void k_ih(
    const float* __restrict__ x,
    const float* __restrict__ wf, const float* __restrict__ wb,
    const float* __restrict__ bif, const float* __restrict__ bhf,
    const float* __restrict__ bib, const float* __restrict__ bhb,
    float* __restrict__ pre) {
  __shared__ __align__(16) float wl[HID_ * 104];
  __shared__ float bs[HID_];
  int bid = blockIdx.x;
  int dir = bid >> 9;
  int blk = bid & 511;
  const float* w = dir ? wb : wf;
  const float* bi = dir ? bib : bif;
  const float* bh = dir ? bhb : bhf;
  int tid = threadIdx.x;
  for (int u = tid; u < HID_; u += 256) bs[u] = bi[u] + bh[u];
  // pass 0: k = 0..103
  for (int u = tid; u < HID_ * 104; u += 256) {
    int j = u / 104, k = u - j * 104;
    wl[u] = w[j * IN_ + k];
  }
  __syncthreads();
  int row = blk * 256 + tid;  // 512 blocks/dir * 256 = 131072
  const float* xr = x + (long)row * IN_;
  float acc[HID_];
#pragma unroll
  for (int j = 0; j < HID_; j++) acc[j] = 0.f;
  for (int kk = 0; kk < 26; kk++) {
    float2 a = *(const float2*)(xr + 4 * kk);
    float2 b = *(const float2*)(xr + 4 * kk + 2);
#pragma unroll
    for (int j = 0; j < HID_; j++) {
      float4 wv = *(const float4*)(&wl[j * 104 + 4 * kk]);
      acc[j] += a.x * wv.x + a.y * wv.y + b.x * wv.z + b.y * wv.w;
    }
  }
  __syncthreads();
  // pass 1: k = 104..201 (98 values)
  for (int u = tid; u < HID_ * 98; u += 256) {
    int j = u / 98, k = u - j * 98;
    wl[j * 104 + k] = w[j * IN_ + 104 + k];
  }
  __syncthreads();
  for (int kk = 0; kk < 24; kk++) {
    float2 a = *(const float2*)(xr + 104 + 4 * kk);
    float2 b = *(const float2*)(xr + 104 + 4 * kk + 2);
#pragma unroll
    for (int j = 0; j < HID_; j++) {
      float4 wv = *(const float4*)(&wl[j * 104 + 4 * kk]);
      acc[j] += a.x * wv.x + a.y * wv.y + b.x * wv.z + b.y * wv.w;
    }
  }
  {  // tail k = 200,201 -> staged at offset 96,97
    float2 a = *(const float2*)(xr + 200);
#pragma unroll
    for (int j = 0; j < HID_; j++) {
      float2 wv = *(const float2*)(&wl[j * 104 + 96]);
      acc[j] += a.x * wv.x + a.y * wv.y;
    }
  }
  float* o = pre + (long)row * 200 + dir * 100;
#pragma unroll
  for (int j = 0; j < HID_; j++) o[j] = acc[j] + bs[j];
}

// ---------------- K2: in-place recurrence over b (256 steps), one wave per (t,dir)
__global__ __launch_bounds__(64, 1) void k_rnn(
    float* __restrict__ pre,
    const float* __restrict__ whf, const float* __restrict__ whb) {
  int bid = blockIdx.x;
  int dir = bid >> 9;
  int t = bid & 511;
  const float* w = dir ? whb : whf;
  int lane = threadIdx.x;
  int r1 = lane + 64; if (r1 > 99) r1 = 99;  // clamped (lanes>=36 compute discarded h1)
  float w0[HID_], w1[HID_];
#pragma unroll
  for (int kk = 0; kk < 25; kk++) {
    float4 a = *(const float4*)(w + lane * HID_ + 4 * kk);
    w0[4 * kk] = a.x; w0[4 * kk + 1] = a.y; w0[4 * kk + 2] = a.z; w0[4 * kk + 3] = a.w;
    float4 b = *(const float4*)(w + r1 * HID_ + 4 * kk);
    w1[4 * kk] = b.x; w1[4 * kk + 1] = b.y; w1[4 * kk + 2] = b.z; w1[4 * kk + 3] = b.w;
  }
  int o1 = 64 + (lane < 36 ? lane : 35);
  long step = dir ? -(long)(T_ * 200) : (long)(T_ * 200);
  float* p = pre + ((long)(dir ? (B_ - 1) : 0) * T_ + t) * 200 + dir * 100;
  float h0 = 0.f, h1 = 0.f;
  float a0 = p[lane], a1 = p[o1];
  for (int s = 0; s < B_; s++) {
    float n0 = 0.f, n1 = 0.f;
    if (s < B_ - 1) { n0 = p[step + lane]; n1 = p[step + o1]; }
    float s0a = a0, s0b = 0.f, s1a = a1, s1b = 0.f;
#pragma unroll
    for (int k = 0; k < 50; k++) {
      float hk = rl_f(h0, k);
      s0a = fmaf(hk, w0[k], s0a);
      s1a = fmaf(hk, w1[k], s1a);
    }
#pragma unroll
    for (int k = 50; k < 64; k++) {
      float hk = rl_f(h0, k);
      s0b = fmaf(hk, w0[k], s0b);
      s1b = fmaf(hk, w1[k], s1b);
    }
#pragma unroll
    for (int k = 64; k < 100; k++) {
      float hk = rl_f(h1, k - 64);
      s0b = fmaf(hk, w0[k], s0b);
      s1b = fmaf(hk, w1[k], s1b);
    }
    h0 = tanhf(s0a + s0b);
    h1 = tanhf(s1a + s1b);
    p[lane] = h0;
    if (lane < 36) p[o1] = h1;
    p += step;
    a0 = n0; a1 = n1;
  }
}

// ---------------- K3: logits = h @ w_lin^T + b_lin ; softmax over 19
__global__ __launch_bounds__(256, 1) void k_lin(
    const float* __restrict__ h, const float* __restrict__ wlin,
    const float* __restrict__ blin, float* __restrict__ em) {
  __shared__ __align__(16) float wt[K_ * 200];
  int tid = threadIdx.x;
  for (int u = tid; u < K_ * 200; u += 256) wt[u] = wlin[u];
  __syncthreads();
  long m = (long)blockIdx.x * 256 + tid;
  const float* hr = h + m * 200;
  float acc[K_];
#pragma unroll
  for (int c = 0; c < K_; c++) acc[c] = blin[c];
  for (int kk = 0; kk < 50; kk++) {
    float4 hv = *(const float4*)(hr + 4 * kk);
#pragma unroll
    for (int c = 0; c < K_; c++) {
      float4 wv = *(const float4*)(&wt[c * 200 + 4 * kk]);
      acc[c] += hv.x * wv.x + hv.y * wv.y + hv.z * wv.z + hv.w * wv.w;
    }
  }
  float mx = acc[0];
#pragma unroll
  for (int c = 1; c < K_; c++) mx = fmaxf(mx, acc[c]);
  float s = 0.f;
#pragma unroll
  for (int c = 0; c < K_; c++) { acc[c] = __expf(acc[c] - mx); s += acc[c]; }
  float inv = 1.f / s;
  float* er = em + m * K_;
#pragma unroll
  for (int c = 0; c < K_; c++) er[c] = acc[c] * inv;
}

// ---------------- K4: per-b CRF logZ + gold score (wave0) and Viterbi forward (wave1)
__global__ __launch_bounds__(128, 1) void k_crf(
    const float* __restrict__ em, const int* __restrict__ y,
    const float* __restrict__ st_g, const float* __restrict__ en_g,
    const float* __restrict__ tr_g,
    float* __restrict__ part, int* __restrict__ bl,
    unsigned char* __restrict__ hist) {
  __shared__ __align__(16) float es[T_ * K_];
  __shared__ int ys[T_];
  __shared__ float tr[K_ * K_];
  __shared__ float st[K_], en[K_];
  int b = blockIdx.x;
  int tid = threadIdx.x;
  const float4* eb4 = (const float4*)(em + (long)b * T_ * K_);
  for (int u = tid; u < T_ * K_ / 4; u += 128) ((float4*)es)[u] = eb4[u];
  for (int u = tid; u < T_; u += 128) ys[u] = y[b * T_ + u];
  for (int u = tid; u < K_ * K_; u += 128) tr[u] = tr_g[u];
  if (tid < K_) { st[tid] = st_g[tid]; en[tid] = en_g[tid]; }
  __syncthreads();
  int wv = tid >> 6, lane = tid & 63;
  int jj = lane < K_ ? lane : K_ - 1;
  bool act = lane < K_;
  if (wv == 0) {
    float E[K_];
#pragma unroll
    for (int i = 0; i < K_; i++) E[i] = __expf(tr[i * K_ + jj]);
    float z = act ? st[jj] + es[jj] : -1e30f;
    int y0 = ys[0];
    int prev = (y0 != -1) ? y0 : 0;
    float num = st[prev] + es[prev];
    for (int t = 1; t < T_; t++) {
      float e = es[t * K_ + jj];
      int yv = ys[t];
      bool mb = (yv != -1);
      float m = z;
#pragma unroll
      for (int off = 16; off; off >>= 1) m = fmaxf(m, __shfl_xor(m, off, 32));
      float pz = __expf(z - m);
      float acc = 0.f;
#pragma unroll
      for (int i = 0; i < K_; i++) acc = fmaf(rl_f(pz, i), E[i], acc);
      float nz = e + m + __logf(acc);
      if (act && mb) z = nz;
      if (mb) {
        num += tr[prev * K_ + yv] + es[t * K_ + yv];
        prev = yv;
      }
    }
    num += en[prev];
    float zf = z + en[jj];
    float m2 = zf;
#pragma unroll
    for (int off = 16; off; off >>= 1) m2 = fmaxf(m2, __shfl_xor(m2, off, 32));
    float sm = __expf(zf - m2);
#pragma unroll
    for (int off = 16; off; off >>= 1) sm += __shfl_xor(sm, off, 32);
    if (lane == 0) part[b] = m2 + __logf(sm) - num;
  } else {
    float Tt[K_];
#pragma unroll
    for (int i = 0; i < K_; i++) Tt[i] = tr[i * K_ + jj];
    float v = act ? st[jj] + es[jj] : -1e30f;
    unsigned char* hb_ = hist + (long)b * HSTRIDE;
    for (int t = 1; t < T_; t++) {
      float e = es[t * K_ + jj];
      int yv = ys[t];
      bool mb = (yv != -1);
      float b0 = -1e30f, b1 = -1e30f, b2 = -1e30f, b3 = -1e30f;
      int a0 = 0, a1 = 5, a2 = 10, a3 = 15;
#pragma unroll
      for (int i = 0; i < 5; i++)  { float c = rl_f(v, i) + Tt[i]; if (c > b0) { b0 = c; a0 = i; } }
#pragma unroll
      for (int i = 5; i < 10; i++) { float c = rl_f(v, i) + Tt[i]; if (c > b1) { b1 = c; a1 = i; } }
#pragma unroll
      for (int i = 10; i < 15; i++){ float c = rl_f(v, i) + Tt[i]; if (c > b2) { b2 = c; a2 = i; } }
#pragma unroll
      for (int i = 15; i < 19; i++){ float c = rl_f(v, i) + Tt[i]; if (c > b3) { b3 = c; a3 = i; } }
      if (b1 > b0) { b0 = b1; a0 = a1; }
      if (b2 > b0) { b0 = b2; a0 = a2; }
      if (b3 > b0) { b0 = b3; a0 = a3; }
      if (act) hb_[(t - 1) * K_ + lane] = (unsigned char)a0;
      if (act && mb) v = b0 + e;
    }
    float sc = v + en[jj];
    float bb = -1e30f; int aa = 0;
#pragma unroll
    for (int i = 0; i < K_; i++) { float c = rl_f(sc, i); if (c > bb) { bb = c; aa = i; } }
    if (lane == 0) bl[b] = aa;
  }
}

// ---------------- K5: backtrack + label write + loss reduction (block 0)
__global__ __launch_bounds__(64, 1) void k_back(
    const unsigned char* __restrict__ hist, const int* __restrict__ y,
    const int* __restrict__ bl, const float* __restrict__ part,
    float* __restrict__ out) {
  __shared__ __align__(16) unsigned char hl[HSTRIDE];
  __shared__ int ys[T_];
  __shared__ float lab[T_];
  int b = blockIdx.x;
  int tid = threadIdx.x;
  const float4* hs = (const float4*)(hist + (long)b * HSTRIDE);
  for (int u = tid; u < HSTRIDE / 16; u += 64) ((float4*)hl)[u] = hs[u];
  for (int u = tid; u < T_; u += 64) ys[u] = y[b * T_ + u];
  __syncthreads();
  int tag = bl[b];
  if (tid == 0) lab[T_ - 1] = (ys[T_ - 1] != -1) ? (float)tag : -1.f;
  for (int ti = T_ - 2; ti >= 0; ti--) {
    if (ys[ti + 1] != -1) tag = hl[ti * K_ + tag];
    if (tid == 0) lab[ti] = (ys[ti] != -1) ? (float)tag : -1.f;
  }
  __syncthreads();
  float* ob = out + 1 + (long)b * T_;
  for (int u = tid; u < T_; u += 64) ob[u] = lab[u];
  if (b == 0) {
    float s = 0.f;
    for (int u = tid; u < B_; u += 64) s += part[u];
#pragma unroll
    for (int off = 32; off; off >>= 1) s += __shfl_xor(s, off, 64);
    if (tid == 0) out[0] = s;
  }
}

extern "C" void kernel_launch(void* const* d_in, const int* in_sizes, int n_in,
                              void* d_out, int out_size, void* d_ws, size_t ws_size,
                              hipStream_t stream) {
  const float* x      = (const float*)d_in[0];
  const int*   y      = (const int*)d_in[1];
  const float* w_ih_f = (const float*)d_in[2];
  const float* w_hh_f = (const float*)d_in[3];
  const float* b_ih_f = (const float*)d_in[4];
  const float* b_hh_f = (const float*)d_in[5];
  const float* w_ih_b = (const float*)d_in[6];
  const float* w_hh_b = (const float*)d_in[7];
  const float* b_ih_b = (const float*)d_in[8];
  const float* b_hh_b = (const float*)d_in[9];
  const float* w_lin  = (const float*)d_in[10];
  const float* b_lin  = (const float*)d_in[11];
  const float* st     = (const float*)d_in[12];
  const float* en     = (const float*)d_in[13];
  const float* trans  = (const float*)d_in[14];

  char* ws = (char*)d_ws;
  const size_t PRE_OFF  = 0;                         // 131072*200*4 = 104857600
  const size_t EM_OFF   = 104857600;                 // 131072*19*4  = 9961472
  const size_t HIST_OFF = EM_OFF + 9961472;          // 256*9712     = 2486272
  const size_t PART_OFF = HIST_OFF + 2486272;        // 1024
  const size_t BL_OFF   = PART_OFF + 1024;           // 1024
  float* PRE = (float*)(ws + PRE_OFF);
  float* EM  = (float*)(ws + EM_OFF);
  unsigned char* HIST = (unsigned char*)(ws + HIST_OFF);
  float* PART = (float*)(ws + PART_OFF);
  int*   BL   = (int*)(ws + BL_OFF);
  float* out  = (float*)d_out;

  k_ih<<<1024, 256, 0, stream>>>(x, w_ih_f, w_ih_b, b_ih_f, b_hh_f, b_ih_b, b_hh_b, PRE);
  k_rnn<<<1024, 64, 0, stream>>>(PRE, w_hh_f, w_hh_b);
  k_lin<<<512, 256, 0, stream>>>(PRE, w_lin, b_lin, EM);
  k_crf<<<256, 128, 0, stream>>>(EM, y, st, en, trans, PART, BL, HIST);
  k_back<<<256, 64, 0, stream>>>(HIST, y, BL, PART, out);
}